// Round 6
// baseline (569.105 us; speedup 1.0000x reference)
//
#include <hip/hip_runtime.h>
#include <hip/hip_bf16.h>

// MultiScaleAttentionPE — MI355X round 9
// Fold kept: pe = peB[k] @ P_top (bf16 MFMA, K=256)
//               + dxyz @ (W@P_top) + xyz @ (Wall@P_bot) + c   (fp32 exact)
// Round-9: dispatch graph 6 -> 2.
//   Launch 1: prep (P^T transpose + consts fold + inline cls4) + all 3 NN
//             searches, all reading RAW inputs with inline bf16->f32 convert
//             (canon_kernel deleted). Zeroes the phase counters + writes flag.
//   Launch 2: ALL levels fused (L3+pe4 -> L2 -> L1 -> L0) in one kernel with
//             device-scope atomic phase counters. 468 blocks @ 256 thr,
//             __launch_bounds__(256,2) => 2 blocks/CU => all 468 co-resident
//             (capacity 512) => spin-wait is deadlock-free by construction.

typedef __hip_bfloat16 bf16;
typedef unsigned short ushort_t;
typedef __attribute__((ext_vector_type(8))) short short8;
typedef __attribute__((ext_vector_type(4))) float float4v;

#define cN0 65536
#define cN1 16384
#define cN2 4096
#define cN3 1024
#define cN4 256

__device__ __forceinline__ float bits2f(ushort_t u) {
    union { unsigned u; float f; } x; x.u = ((unsigned)u) << 16; return x.f;
}
__device__ __forceinline__ float ldf(const void* raw, int fp32, int i) {
    return fp32 ? ((const float*)raw)[i] : bits2f(((const ushort_t*)raw)[i]);
}
__device__ __forceinline__ float3 ld3(const void* raw, int fp32, int i) {
    if (fp32) {
        const float* f = (const float*)raw + 3 * i;
        return make_float3(f[0], f[1], f[2]);
    }
    const ushort_t* u = (const ushort_t*)raw + 3 * i;
    return make_float3(bits2f(u[0]), bits2f(u[1]), bits2f(u[2]));
}

// RNE float -> bf16 bits (values are finite; no NaN path needed)
__device__ __forceinline__ ushort_t f2b(float v) {
    union { float f; unsigned u; } x; x.f = v;
    unsigned r = x.u + 0x7FFF + ((x.u >> 16) & 1);
    return (ushort_t)(r >> 16);
}

struct RawArgs {
    const void* xyz;
    const void* Wall; const void* ball;
    const void* W[5]; const void* bb[5];
    const void* P[5]; const void* pb[5];
};

// ---------------- launch 1: prep + nn (reads raw inputs) ----------------
// blocks   0..63 : P_top -> P_top^T bf16, levels 1..4 (level=1+(b>>4))
// blocks  64..103: M1/M2/c fold (L=(b-64)>>3, tb=(b-64)&7); L==0 inlines cls4
// blocks 104..439: 1-NN argmin (16 blk k34, 64 blk k23, 256 blk k12)

__device__ __forceinline__ void nn_body(const void* xyzr, int fp32,
                                        const int* __restrict__ idxQ,
                                        const int* __restrict__ idxR, int nR,
                                        int* __restrict__ outK, int blk,
                                        float4* ref4, float* redD, int* redI) {
    int tid = threadIdx.x;
    int part = tid >> 6;                   // 0..7
    int q = blk * 64 + (tid & 63);
    int qi = idxQ[q];
    float3 qv = ld3(xyzr, fp32, qi);
    float qx = qv.x, qy = qv.y, qz = qv.z;
    float q2 = (qx * qx + qy * qy) + qz * qz;
    float best = 3.402823466e38f;
    int bi = 0;
    for (int base = 0; base < nR; base += 1024) {
        int nt = min(1024, nR - base);
        __syncthreads();
        for (int t = tid; t < nt; t += 512) {
            int ri = idxR[base + t];
            float3 r3 = ld3(xyzr, fp32, ri);
            ref4[t] = make_float4(r3.x, r3.y, r3.z,
                                  (r3.x * r3.x + r3.y * r3.y) + r3.z * r3.z);
        }
        __syncthreads();
        int seg = nt >> 3;
        int s0 = part * seg;
        for (int t = 0; t < seg; ++t) {
            float4 rp = ref4[s0 + t];
            float dot = (qx * rp.x + qy * rp.y) + qz * rp.z;
            float d = (q2 - 2.0f * dot) + rp.w;
            if (d < best) { best = d; bi = base + s0 + t; }
        }
    }
    redD[tid] = best;
    redI[tid] = bi;
    __syncthreads();
    if (part == 0) {
#pragma unroll
        for (int p = 1; p < 8; ++p) {
            float d = redD[tid + p * 64];
            int i2 = redI[tid + p * 64];
            if (d < best || (d == best && i2 < bi)) { best = d; bi = i2; }
        }
        outK[q] = bi;
    }
}

__global__ void prep_nn_kernel(RawArgs ra,
                               const int* __restrict__ idx1, const int* __restrict__ idx2,
                               const int* __restrict__ idx3, const int* __restrict__ idx4,
                               ushort_t* __restrict__ PTb,
                               float* __restrict__ M1, float* __restrict__ M2,
                               float* __restrict__ cbuf,
                               int* __restrict__ k34, int* __restrict__ k23,
                               int* __restrict__ k12,
                               int* __restrict__ flag, int* __restrict__ cnt) {
    __shared__ __align__(16) char smem[20608];
    __shared__ int sbad;
    int b = blockIdx.x;
    int tid = threadIdx.x;

    // inline dtype detect (identical arithmetic to prior canon/detect)
    if (tid == 0) sbad = 0;
    __syncthreads();
    {
        const ushort_t* raw0 = (const ushort_t*)ra.xyz;
        for (int i = tid; i < 1024; i += 512) {
            int e = (raw0[i] >> 7) & 0xFF;
            if (e >= 138) atomicOr(&sbad, 1);
        }
    }
    __syncthreads();
    int fp32 = sbad ? 1 : 0;
    if (b == 0 && tid == 0) {
        flag[0] = fp32;
        cnt[0] = 0; cnt[1] = 0; cnt[2] = 0;
    }

    if (b < 64) {
        // ---- transpose path: levels 1..4 ----
        int level = 1 + (b >> 4);
        int kb = (b >> 2) & 3;
        int nb = b & 3;
        const void* P = ra.P[level];
        ushort_t* PT = PTb + (size_t)level * 65536;
        float (*tile)[65] = (float (*)[65])smem;
        int tx = tid & 63, ty = tid >> 6;          // ty 0..7
        for (int r = ty; r < 64; r += 8)
            tile[r][tx] = ldf(P, fp32, (kb * 64 + r) * 256 + nb * 64 + tx);
        __syncthreads();
        for (int r = ty; r < 64; r += 8)
            PT[(size_t)(nb * 64 + r) * 256 + kb * 64 + tx] = f2b(tile[tx][r]);
        return;
    }

    if (b < 104) {
        // ---- consts path ----
        int L = (b - 64) >> 3;
        int tb = (b - 64) & 7;
        const void* P = ra.P[L];
        const void* W = ra.W[L];
        const void* bvec = ra.bb[L];
        const void* pb = ra.pb[L];
        float* cls4f = (float*)smem;                 // 256
        float* red = (float*)(smem + 1024);          // 7*256
        float* px = (float*)(smem + 1024 + 7168);
        float* py = px + 256;
        float* pz = py + 256;

        if (L == 0) {
            if (tid < 256) {
                float3 x = ld3(ra.xyz, fp32, tid);
                px[tid] = x.x; py[tid] = x.y; pz[tid] = x.z;
            }
            __syncthreads();
            if (tid < 256) {
                float w0 = ldf(ra.Wall, fp32, tid);
                float w1 = ldf(ra.Wall, fp32, 256 + tid);
                float w2 = ldf(ra.Wall, fp32, 512 + tid);
                float bbv = ldf(ra.ball, fp32, tid);
                float best = -3.402823466e38f;
                for (int i = 0; i < 256; ++i) {
                    float v = fmaf(pz[i], w2, fmaf(py[i], w1, px[i] * w0)) + bbv;
                    best = fmaxf(best, v);
                }
                cls4f[tid] = best;
            }
            __syncthreads();
        }

        if (tid < 256) {
            int j = tid & 31;
            int slice = tid >> 5;
            int col = tb * 32 + j;
            float m10 = 0.f, m11 = 0.f, m12 = 0.f, m20 = 0.f, m21 = 0.f, m22 = 0.f, cc = 0.f;
#pragma unroll 4
            for (int i = 0; i < 32; ++i) {
                int c = slice * 32 + i;
                float pt = ldf(P, fp32, c * 256 + col);
                float pbot = ldf(P, fp32, (256 + c) * 256 + col);
                m10 = fmaf(ldf(W, fp32, c), pt, m10);
                m11 = fmaf(ldf(W, fp32, 256 + c), pt, m11);
                m12 = fmaf(ldf(W, fp32, 512 + c), pt, m12);
                m20 = fmaf(ldf(ra.Wall, fp32, c), pbot, m20);
                m21 = fmaf(ldf(ra.Wall, fp32, 256 + c), pbot, m21);
                m22 = fmaf(ldf(ra.Wall, fp32, 512 + c), pbot, m22);
                cc = fmaf(ldf(bvec, fp32, c), pt, cc);
                cc = fmaf(ldf(ra.ball, fp32, c), pbot, cc);
                if (L == 0) cc = fmaf(cls4f[c], pt, cc);
            }
            red[0 * 256 + tid] = m10; red[1 * 256 + tid] = m11; red[2 * 256 + tid] = m12;
            red[3 * 256 + tid] = m20; red[4 * 256 + tid] = m21; red[5 * 256 + tid] = m22;
            red[6 * 256 + tid] = cc;
        }
        __syncthreads();
        if (tid < 32) {
            int col = tb * 32 + tid;
            float v[7];
#pragma unroll
            for (int q = 0; q < 7; ++q) {
                float s = red[q * 256 + tid];
#pragma unroll
                for (int sl = 1; sl < 8; ++sl) s += red[q * 256 + sl * 32 + tid];
                v[q] = s;
            }
            M1[(size_t)L * 768 + col] = v[0];
            M1[(size_t)L * 768 + 256 + col] = v[1];
            M1[(size_t)L * 768 + 512 + col] = v[2];
            M2[(size_t)L * 768 + col] = v[3];
            M2[(size_t)L * 768 + 256 + col] = v[4];
            M2[(size_t)L * 768 + 512 + col] = v[5];
            cbuf[(size_t)L * 256 + col] = v[6] + ldf(pb, fp32, col);
        }
        return;
    }

    // ---- nn path ----
    int blk = b - 104;
    float4* ref4 = (float4*)smem;              // 1024 * 16B
    float* redD = (float*)(smem + 16384);      // 512
    int* redI = (int*)(smem + 18432);          // 512
    if (blk < 16)       nn_body(ra.xyz, fp32, idx3, idx4, cN4, k34, blk, ref4, redD, redI);
    else if (blk < 80)  nn_body(ra.xyz, fp32, idx2, idx3, cN3, k23, blk - 16, ref4, redD, redI);
    else                nn_body(ra.xyz, fp32, idx1, idx2, cN2, k12, blk - 80, ref4, redD, redI);
}

// ---------------- launch 2: ALL levels fused ----------------
// blocks   0..15 : L3 MFMA tiles (A built from rank-6 affine pe4 form) -> cnt[0]
// blocks  16..19 : pe4 output writers (independent)
// blocks  20..83 : L2 tiles, spin cnt[0]==16  -> cnt[1]
// blocks  84..211: L1, 2 tiles each, spin cnt[1]==64 -> cnt[2]
// blocks 212..467: L0, 4 tiles each, spin cnt[2]==128
// 468 blocks @ 256thr, launch_bounds(256,2) => all co-resident => no deadlock.
__global__ __launch_bounds__(256, 2) void levels_kernel(
    const void* __restrict__ xyz_raw,
    const int* __restrict__ idx0, const int* __restrict__ idx1,
    const int* __restrict__ idx2, const int* __restrict__ idx3,
    const int* __restrict__ idx4,
    const int* __restrict__ k34, const int* __restrict__ k23,
    const int* __restrict__ k12,
    const float* __restrict__ M1buf, const float* __restrict__ M2buf,
    const float* __restrict__ cbuf,
    const ushort_t* __restrict__ PTb,
    const int* __restrict__ flag, void* __restrict__ outv,
    ushort_t* __restrict__ pe3B, ushort_t* __restrict__ pe2B,
    ushort_t* __restrict__ pe1B,
    int* __restrict__ cnt) {
    __shared__ float m1l[768], m2l[768], cl[256];
    __shared__ float rowD[64][3], rowX[64][3], refQ[64][3], refK[64][3];
    __shared__ int rowK[64];
    __shared__ __align__(16) ushort_t A_lds[64 * 264];

    int b = blockIdx.x;
    int tid = threadIdx.x;
    int fp32 = flag[0];

    const size_t o4 = 0;
    const size_t o3 = 65536;
    const size_t o2 = 327680;
    const size_t o1 = 1376256;
    const size_t o0 = 5570560;

    if (b >= 16 && b < 20) {
        // ---- pe4 output writers (exact pe4 fmaf chain) ----
        int rows0 = (b - 16) * 64;
        if (tid < 64) {
            int k = rows0 + tid;
            float3 q = ld3(xyz_raw, fp32, idx4[k]);
            float3 x = ld3(xyz_raw, fp32, k);
            refQ[tid][0] = q.x; refQ[tid][1] = q.y; refQ[tid][2] = q.z;
            refK[tid][0] = x.x; refK[tid][1] = x.y; refK[tid][2] = x.z;
        }
        __syncthreads();
        float cc = cbuf[tid];
        float a0 = M1buf[tid], a1 = M1buf[256 + tid], a2 = M1buf[512 + tid];
        float b0 = M2buf[tid], b1 = M2buf[256 + tid], b2 = M2buf[512 + tid];
        for (int r = 0; r < 64; ++r) {
            float v = cc;
            v = fmaf(refQ[r][0], a0, v);
            v = fmaf(refQ[r][1], a1, v);
            v = fmaf(refQ[r][2], a2, v);
            v = fmaf(refK[r][0], b0, v);
            v = fmaf(refK[r][1], b1, v);
            v = fmaf(refK[r][2], b2, v);
            size_t idx = o4 + (size_t)(rows0 + r) * 256 + tid;
            if (fp32) ((float*)outv)[idx] = v;
            else      ((bf16*)outv)[idx] = __float2bfloat16(v);
        }
        return;
    }

    int level, t0, tcnt;
    const int* kmap; const int* idxQ; const int* idxR;
    const ushort_t* peprev; ushort_t* peout;
    size_t ooff;
    const float* M1; const float* M2; const float* cv;
    const ushort_t* PT;
    int* waitc = nullptr; int target = 0; int* donec = nullptr;

    if (b < 16) {
        level = 3; t0 = b; tcnt = 1;
        kmap = k34; idxQ = idx3; idxR = idx4;
        peprev = nullptr; peout = pe3B; ooff = o3;
        M1 = M1buf + 768; M2 = M2buf + 768; cv = cbuf + 256;
        PT = PTb + 1 * 65536;
        donec = cnt + 0;
    } else if (b < 84) {
        level = 2; t0 = b - 20; tcnt = 1;
        kmap = k23; idxQ = idx2; idxR = idx3;
        peprev = pe3B; peout = pe2B; ooff = o2;
        M1 = M1buf + 1536; M2 = M2buf + 1536; cv = cbuf + 512;
        PT = PTb + 2 * 65536;
        waitc = cnt + 0; target = 16; donec = cnt + 1;
    } else if (b < 212) {
        level = 1; t0 = (b - 84) * 2; tcnt = 2;
        kmap = k12; idxQ = idx1; idxR = idx2;
        peprev = pe2B; peout = pe1B; ooff = o1;
        M1 = M1buf + 2304; M2 = M2buf + 2304; cv = cbuf + 768;
        PT = PTb + 3 * 65536;
        waitc = cnt + 1; target = 64; donec = cnt + 2;
    } else {
        level = 0; t0 = (b - 212) * 4; tcnt = 4;
        kmap = idx0; idxQ = nullptr; idxR = idx1;
        peprev = pe1B; peout = nullptr; ooff = o0;
        M1 = M1buf + 3072; M2 = M2buf + 3072; cv = cbuf + 1024;
        PT = PTb + 4 * 65536;
        waitc = cnt + 2; target = 128; donec = nullptr;
    }

    // preload per-level consts BEFORE spinning (overlaps the wait)
    for (int i = tid; i < 768; i += 256) { m1l[i] = M1[i]; m2l[i] = M2[i]; }
    cl[tid] = cv[tid];

    if (waitc) {
        if (tid == 0) {
            while (__hip_atomic_load(waitc, __ATOMIC_ACQUIRE, __HIP_MEMORY_SCOPE_AGENT) < target)
                __builtin_amdgcn_s_sleep(8);
        }
        __syncthreads();
    }

    int wave = tid >> 6;
    int lane = tid & 63;
    int quad = lane >> 4;
    int l16 = lane & 15;
    int wc = wave * 64;

    const ushort_t* bbase[4];
#pragma unroll
    for (int nt = 0; nt < 4; ++nt)
        bbase[nt] = PT + (size_t)(wc + nt * 16 + l16) * 256 + quad * 8;

    for (int tt = 0; tt < tcnt; ++tt) {
        int row0 = (t0 + tt) * 64;
        __syncthreads();
        if (tid < 64) {
            int r = tid, row = row0 + r;
            float3 x = ld3(xyz_raw, fp32, row);
            rowX[r][0] = x.x; rowX[r][1] = x.y; rowX[r][2] = x.z;
            int k = kmap[row];
            rowK[r] = k;
            float qx = x.x, qy = x.y, qz = x.z;
            if (idxQ) {
                float3 q = ld3(xyz_raw, fp32, idxQ[row]);
                qx = q.x; qy = q.y; qz = q.z;
            }
            int ri = idxR[k];
            float3 rr = ld3(xyz_raw, fp32, ri);
            rowD[r][0] = qx - rr.x; rowD[r][1] = qy - rr.y; rowD[r][2] = qz - rr.z;
            if (level == 3) {
                refQ[r][0] = rr.x; refQ[r][1] = rr.y; refQ[r][2] = rr.z;
                float3 kk = ld3(xyz_raw, fp32, k);
                refK[r][0] = kk.x; refK[r][1] = kk.y; refK[r][2] = kk.z;
            }
        }
        __syncthreads();

        if (level == 3) {
            // A rows = pe4[rowK[r]] via rank-6 affine (bit-identical chain)
            float cc = cbuf[tid];
            float a0 = M1buf[tid], a1 = M1buf[256 + tid], a2 = M1buf[512 + tid];
            float b0 = M2buf[tid], b1 = M2buf[256 + tid], b2 = M2buf[512 + tid];
            for (int r = 0; r < 64; ++r) {
                float v = cc;
                v = fmaf(refQ[r][0], a0, v);
                v = fmaf(refQ[r][1], a1, v);
                v = fmaf(refQ[r][2], a2, v);
                v = fmaf(refK[r][0], b0, v);
                v = fmaf(refK[r][1], b1, v);
                v = fmaf(refK[r][2], b2, v);
                A_lds[r * 264 + tid] = f2b(v);
            }
        } else {
#pragma unroll
            for (int it = 0; it < 8; ++it) {
                int lin = it * 256 + tid;
                int r = lin >> 5, ch = lin & 31;
                *(uint4*)&A_lds[r * 264 + ch * 8] =
                    *(const uint4*)(peprev + (size_t)rowK[r] * 256 + ch * 8);
            }
        }
        __syncthreads();

        float4v acc[4][4];
#pragma unroll
        for (int mt = 0; mt < 4; ++mt)
#pragma unroll
            for (int nt = 0; nt < 4; ++nt) acc[mt][nt] = (float4v){0.f, 0.f, 0.f, 0.f};

#pragma unroll
        for (int kt = 0; kt < 8; ++kt) {
            int c0 = kt * 32;
            short8 afr[4], bfr[4];
#pragma unroll
            for (int nt = 0; nt < 4; ++nt)
                bfr[nt] = *(const short8*)(bbase[nt] + c0);
#pragma unroll
            for (int mt = 0; mt < 4; ++mt)
                afr[mt] = *(const short8*)&A_lds[(mt * 16 + l16) * 264 + c0 + quad * 8];
#pragma unroll
            for (int mt = 0; mt < 4; ++mt)
#pragma unroll
                for (int nt = 0; nt < 4; ++nt)
                    acc[mt][nt] = __builtin_amdgcn_mfma_f32_16x16x32_bf16(
                        afr[mt], bfr[nt], acc[mt][nt], 0, 0, 0);
        }

#pragma unroll
        for (int mt = 0; mt < 4; ++mt) {
#pragma unroll
            for (int reg = 0; reg < 4; ++reg) {
                int rl = mt * 16 + quad * 4 + reg;
                float d0 = rowD[rl][0], d1 = rowD[rl][1], d2 = rowD[rl][2];
                float x0 = rowX[rl][0], x1 = rowX[rl][1], x2 = rowX[rl][2];
                int row = row0 + rl;
#pragma unroll
                for (int nt = 0; nt < 4; ++nt) {
                    int col = wc + nt * 16 + l16;
                    float v = acc[mt][nt][reg] + cl[col];
                    v = fmaf(d0, m1l[col], v);
                    v = fmaf(d1, m1l[256 + col], v);
                    v = fmaf(d2, m1l[512 + col], v);
                    v = fmaf(x0, m2l[col], v);
                    v = fmaf(x1, m2l[256 + col], v);
                    v = fmaf(x2, m2l[512 + col], v);
                    size_t idx = (size_t)row * 256 + col;
                    if (fp32) ((float*)outv)[ooff + idx] = v;
                    else      ((bf16*)outv)[ooff + idx] = __float2bfloat16(v);
                    if (peout) peout[idx] = f2b(v);
                }
            }
        }
    }

    if (donec) {
        __threadfence();            // release this thread's pe writes (agent scope)
        __syncthreads();            // all threads' fences before the signal
        if (tid == 0)
            __hip_atomic_fetch_add(donec, 1, __ATOMIC_RELEASE, __HIP_MEMORY_SCOPE_AGENT);
    }
}

extern "C" void kernel_launch(void* const* d_in, const int* in_sizes, int n_in,
                              void* d_out, int out_size, void* d_ws, size_t ws_size,
                              hipStream_t stream) {
    const int* idx0 = (const int*)d_in[1];
    const int* idx1 = (const int*)d_in[2];
    const int* idx2 = (const int*)d_in[3];
    const int* idx3 = (const int*)d_in[4];
    const int* idx4 = (const int*)d_in[5];

    // workspace layout (all offsets multiples of 64 floats => 16B aligned)
    float* ws = (float*)d_ws;
    int* flag = (int*)ws;            // ws[0]
    int* cnt = (int*)ws + 1;         // ws[1..3] phase counters
    float* p = ws + 64;
    float* M1buf = p; p += 5 * 768;
    float* M2buf = p; p += 5 * 768;
    float* cbuf = p;  p += 5 * 256;
    int* k34 = (int*)p; p += 1024;
    int* k23 = (int*)p; p += 4096;
    int* k12 = (int*)p; p += 16384;
    ushort_t* pe3B = (ushort_t*)p; p += 131072;    // 1024*256 bf16
    ushort_t* pe2B = (ushort_t*)p; p += 524288;    // 4096*256 bf16
    ushort_t* pe1B = (ushort_t*)p; p += 2097152;   // 16384*256 bf16
    ushort_t* PTb = (ushort_t*)p;                  // 5 * 65536 bf16 (slots 1..4 used)

    RawArgs ra;
    ra.xyz = d_in[0];
    ra.Wall = d_in[6];
    ra.ball = d_in[7];
    for (int i = 0; i < 5; ++i) {
        ra.W[i] = d_in[8 + 2 * i];
        ra.bb[i] = d_in[9 + 2 * i];
        ra.P[i] = d_in[18 + 2 * i];
        ra.pb[i] = d_in[19 + 2 * i];
    }

    prep_nn_kernel<<<440, 512, 0, stream>>>(ra, idx1, idx2, idx3, idx4,
                                            PTb, M1buf, M2buf, cbuf,
                                            k34, k23, k12, flag, cnt);

    levels_kernel<<<468, 256, 0, stream>>>(
        d_in[0], idx0, idx1, idx2, idx3, idx4,
        k34, k23, k12, M1buf, M2buf, cbuf, PTb,
        flag, d_out, pe3B, pe2B, pe1B, cnt);
}

// Round 7
// 251.555 us; speedup vs baseline: 2.2623x; 2.2623x over previous
//
#include <hip/hip_runtime.h>
#include <hip/hip_bf16.h>

// MultiScaleAttentionPE — MI355X round 10
// Fold kept: pe = peB[k] @ P_top (bf16 MFMA, K=256)
//               + dxyz @ (W@P_top) + xyz @ (Wall@P_bot) + c   (fp32 exact)
// Round-10: revert round-9's fused producer/consumer kernel (cross-XCD
//   acquire/release made it 417us). Back to round-8's kernel-per-level chain,
//   KEEPING round-9's canon deletion: all kernels read raw inputs with inline
//   bf16->f32 converts. 5 launches total.

typedef __hip_bfloat16 bf16;
typedef unsigned short ushort_t;
typedef __attribute__((ext_vector_type(8))) short short8;
typedef __attribute__((ext_vector_type(4))) float float4v;

#define cN0 65536
#define cN1 16384
#define cN2 4096
#define cN3 1024
#define cN4 256

__device__ __forceinline__ float bits2f(ushort_t u) {
    union { unsigned u; float f; } x; x.u = ((unsigned)u) << 16; return x.f;
}
__device__ __forceinline__ float ldf(const void* raw, int fp32, int i) {
    return fp32 ? ((const float*)raw)[i] : bits2f(((const ushort_t*)raw)[i]);
}
__device__ __forceinline__ float3 ld3(const void* raw, int fp32, int i) {
    if (fp32) {
        const float* f = (const float*)raw + 3 * i;
        return make_float3(f[0], f[1], f[2]);
    }
    const ushort_t* u = (const ushort_t*)raw + 3 * i;
    return make_float3(bits2f(u[0]), bits2f(u[1]), bits2f(u[2]));
}

// RNE float -> bf16 bits (values are finite; no NaN path needed)
__device__ __forceinline__ ushort_t f2b(float v) {
    union { float f; unsigned u; } x; x.f = v;
    unsigned r = x.u + 0x7FFF + ((x.u >> 16) & 1);
    return (ushort_t)(r >> 16);
}

struct RawArgs {
    const void* xyz;
    const void* Wall; const void* ball;
    const void* W[5]; const void* bb[5];
    const void* P[5]; const void* pb[5];
};

// ---------------- launch 1: prep + nn (reads raw inputs) ----------------
// blocks   0..63 : P_top -> P_top^T bf16, levels 1..4 (level=1+(b>>4))
// blocks  64..103: M1/M2/c fold (L=(b-64)>>3, tb=(b-64)&7); L==0 inlines cls4
// blocks 104..439: 1-NN argmin (16 blk k34, 64 blk k23, 256 blk k12)

__device__ __forceinline__ void nn_body(const void* xyzr, int fp32,
                                        const int* __restrict__ idxQ,
                                        const int* __restrict__ idxR, int nR,
                                        int* __restrict__ outK, int blk,
                                        float4* ref4, float* redD, int* redI) {
    int tid = threadIdx.x;
    int part = tid >> 6;                   // 0..7
    int q = blk * 64 + (tid & 63);
    int qi = idxQ[q];
    float3 qv = ld3(xyzr, fp32, qi);
    float qx = qv.x, qy = qv.y, qz = qv.z;
    float q2 = (qx * qx + qy * qy) + qz * qz;
    float best = 3.402823466e38f;
    int bi = 0;
    for (int base = 0; base < nR; base += 1024) {
        int nt = min(1024, nR - base);
        __syncthreads();
        for (int t = tid; t < nt; t += 512) {
            int ri = idxR[base + t];
            float3 r3 = ld3(xyzr, fp32, ri);
            ref4[t] = make_float4(r3.x, r3.y, r3.z,
                                  (r3.x * r3.x + r3.y * r3.y) + r3.z * r3.z);
        }
        __syncthreads();
        int seg = nt >> 3;
        int s0 = part * seg;
        for (int t = 0; t < seg; ++t) {
            float4 rp = ref4[s0 + t];
            float dot = (qx * rp.x + qy * rp.y) + qz * rp.z;
            float d = (q2 - 2.0f * dot) + rp.w;
            if (d < best) { best = d; bi = base + s0 + t; }
        }
    }
    redD[tid] = best;
    redI[tid] = bi;
    __syncthreads();
    if (part == 0) {
#pragma unroll
        for (int p = 1; p < 8; ++p) {
            float d = redD[tid + p * 64];
            int i2 = redI[tid + p * 64];
            if (d < best || (d == best && i2 < bi)) { best = d; bi = i2; }
        }
        outK[q] = bi;
    }
}

__global__ void prep_nn_kernel(RawArgs ra,
                               const int* __restrict__ idx1, const int* __restrict__ idx2,
                               const int* __restrict__ idx3, const int* __restrict__ idx4,
                               ushort_t* __restrict__ PTb,
                               float* __restrict__ M1, float* __restrict__ M2,
                               float* __restrict__ cbuf,
                               int* __restrict__ k34, int* __restrict__ k23,
                               int* __restrict__ k12,
                               int* __restrict__ flag) {
    __shared__ __align__(16) char smem[20608];
    __shared__ int sbad;
    int b = blockIdx.x;
    int tid = threadIdx.x;

    // inline dtype detect (identical arithmetic to original detect)
    if (tid == 0) sbad = 0;
    __syncthreads();
    {
        const ushort_t* raw0 = (const ushort_t*)ra.xyz;
        for (int i = tid; i < 1024; i += 512) {
            int e = (raw0[i] >> 7) & 0xFF;
            if (e >= 138) atomicOr(&sbad, 1);
        }
    }
    __syncthreads();
    int fp32 = sbad ? 1 : 0;
    if (b == 0 && tid == 0) flag[0] = fp32;

    if (b < 64) {
        // ---- transpose path: levels 1..4 ----
        int level = 1 + (b >> 4);
        int kb = (b >> 2) & 3;
        int nb = b & 3;
        const void* P = ra.P[level];
        ushort_t* PT = PTb + (size_t)level * 65536;
        float (*tile)[65] = (float (*)[65])smem;
        int tx = tid & 63, ty = tid >> 6;          // ty 0..7
        for (int r = ty; r < 64; r += 8)
            tile[r][tx] = ldf(P, fp32, (kb * 64 + r) * 256 + nb * 64 + tx);
        __syncthreads();
        for (int r = ty; r < 64; r += 8)
            PT[(size_t)(nb * 64 + r) * 256 + kb * 64 + tx] = f2b(tile[tx][r]);
        return;
    }

    if (b < 104) {
        // ---- consts path ----
        int L = (b - 64) >> 3;
        int tb = (b - 64) & 7;
        const void* P = ra.P[L];
        const void* W = ra.W[L];
        const void* bvec = ra.bb[L];
        const void* pb = ra.pb[L];
        float* cls4f = (float*)smem;                 // 256
        float* red = (float*)(smem + 1024);          // 7*256
        float* px = (float*)(smem + 1024 + 7168);
        float* py = px + 256;
        float* pz = py + 256;

        if (L == 0) {
            if (tid < 256) {
                float3 x = ld3(ra.xyz, fp32, tid);
                px[tid] = x.x; py[tid] = x.y; pz[tid] = x.z;
            }
            __syncthreads();
            if (tid < 256) {
                float w0 = ldf(ra.Wall, fp32, tid);
                float w1 = ldf(ra.Wall, fp32, 256 + tid);
                float w2 = ldf(ra.Wall, fp32, 512 + tid);
                float bbv = ldf(ra.ball, fp32, tid);
                float best = -3.402823466e38f;
                for (int i = 0; i < 256; ++i) {
                    float v = fmaf(pz[i], w2, fmaf(py[i], w1, px[i] * w0)) + bbv;
                    best = fmaxf(best, v);
                }
                cls4f[tid] = best;
            }
            __syncthreads();
        }

        if (tid < 256) {
            int j = tid & 31;
            int slice = tid >> 5;
            int col = tb * 32 + j;
            float m10 = 0.f, m11 = 0.f, m12 = 0.f, m20 = 0.f, m21 = 0.f, m22 = 0.f, cc = 0.f;
#pragma unroll 4
            for (int i = 0; i < 32; ++i) {
                int c = slice * 32 + i;
                float pt = ldf(P, fp32, c * 256 + col);
                float pbot = ldf(P, fp32, (256 + c) * 256 + col);
                m10 = fmaf(ldf(W, fp32, c), pt, m10);
                m11 = fmaf(ldf(W, fp32, 256 + c), pt, m11);
                m12 = fmaf(ldf(W, fp32, 512 + c), pt, m12);
                m20 = fmaf(ldf(ra.Wall, fp32, c), pbot, m20);
                m21 = fmaf(ldf(ra.Wall, fp32, 256 + c), pbot, m21);
                m22 = fmaf(ldf(ra.Wall, fp32, 512 + c), pbot, m22);
                cc = fmaf(ldf(bvec, fp32, c), pt, cc);
                cc = fmaf(ldf(ra.ball, fp32, c), pbot, cc);
                if (L == 0) cc = fmaf(cls4f[c], pt, cc);
            }
            red[0 * 256 + tid] = m10; red[1 * 256 + tid] = m11; red[2 * 256 + tid] = m12;
            red[3 * 256 + tid] = m20; red[4 * 256 + tid] = m21; red[5 * 256 + tid] = m22;
            red[6 * 256 + tid] = cc;
        }
        __syncthreads();
        if (tid < 32) {
            int col = tb * 32 + tid;
            float v[7];
#pragma unroll
            for (int q = 0; q < 7; ++q) {
                float s = red[q * 256 + tid];
#pragma unroll
                for (int sl = 1; sl < 8; ++sl) s += red[q * 256 + sl * 32 + tid];
                v[q] = s;
            }
            M1[(size_t)L * 768 + col] = v[0];
            M1[(size_t)L * 768 + 256 + col] = v[1];
            M1[(size_t)L * 768 + 512 + col] = v[2];
            M2[(size_t)L * 768 + col] = v[3];
            M2[(size_t)L * 768 + 256 + col] = v[4];
            M2[(size_t)L * 768 + 512 + col] = v[5];
            cbuf[(size_t)L * 256 + col] = v[6] + ldf(pb, fp32, col);
        }
        return;
    }

    // ---- nn path ----
    int blk = b - 104;
    float4* ref4 = (float4*)smem;              // 1024 * 16B
    float* redD = (float*)(smem + 16384);      // 512
    int* redI = (int*)(smem + 18432);          // 512
    if (blk < 16)       nn_body(ra.xyz, fp32, idx3, idx4, cN4, k34, blk, ref4, redD, redI);
    else if (blk < 80)  nn_body(ra.xyz, fp32, idx2, idx3, cN3, k23, blk - 16, ref4, redD, redI);
    else                nn_body(ra.xyz, fp32, idx1, idx2, cN2, k12, blk - 80, ref4, redD, redI);
}

// ---------------- level 3 kernel: inline pe4 A-build + pe4 output blocks ----------------
// blocks 0..15 : 64-row L3 MFMA tiles; A rows from the rank-6 affine pe4 form
//                (bit-identical fmaf chain + f2b), staged once in LDS.
// blocks 16..19: write pe4 output region (64 rows each).
__global__ __launch_bounds__(256, 2) void level3_kernel(
    const void* __restrict__ xyz_raw,
    const int* __restrict__ idx3, const int* __restrict__ idx4,
    const int* __restrict__ k34,
    const float* __restrict__ M1_0, const float* __restrict__ M2_0,
    const float* __restrict__ c0,
    const float* __restrict__ M1_1, const float* __restrict__ M2_1,
    const float* __restrict__ c1,
    const ushort_t* __restrict__ PT,
    const int* __restrict__ flag, void* __restrict__ outv,
    size_t o4, size_t o3, ushort_t* __restrict__ peB_out) {
    __shared__ float m1l[768], m2l[768], cl[256];
    __shared__ float rowD[64][3], rowX[64][3], refQ[64][3], refK[64][3];
    __shared__ int rowK[64];
    __shared__ __align__(16) ushort_t A_lds[64 * 264];

    int tid = threadIdx.x;
    int b = blockIdx.x;
    int fp32 = flag[0];

    if (b >= 16) {
        // ---- pe4 output writers (exact pe4 fmaf chain) ----
        int rows0 = (b - 16) * 64;
        if (tid < 64) {
            int k = rows0 + tid;
            float3 q = ld3(xyz_raw, fp32, idx4[k]);
            float3 x = ld3(xyz_raw, fp32, k);
            refQ[tid][0] = q.x; refQ[tid][1] = q.y; refQ[tid][2] = q.z;
            refK[tid][0] = x.x; refK[tid][1] = x.y; refK[tid][2] = x.z;
        }
        __syncthreads();
        float cc = c0[tid];
        float a0 = M1_0[tid], a1 = M1_0[256 + tid], a2 = M1_0[512 + tid];
        float b0 = M2_0[tid], b1 = M2_0[256 + tid], b2 = M2_0[512 + tid];
        for (int r = 0; r < 64; ++r) {
            float v = cc;
            v = fmaf(refQ[r][0], a0, v);
            v = fmaf(refQ[r][1], a1, v);
            v = fmaf(refQ[r][2], a2, v);
            v = fmaf(refK[r][0], b0, v);
            v = fmaf(refK[r][1], b1, v);
            v = fmaf(refK[r][2], b2, v);
            size_t idx = o4 + (size_t)(rows0 + r) * 256 + tid;
            if (fp32) ((float*)outv)[idx] = v;
            else      ((bf16*)outv)[idx] = __float2bfloat16(v);
        }
        return;
    }

    // ---- L3 MFMA tile ----
    int row0 = b * 64;
    for (int i = tid; i < 768; i += 256) { m1l[i] = M1_1[i]; m2l[i] = M2_1[i]; }
    cl[tid] = c1[tid];
    if (tid < 64) {
        int r = tid, row = row0 + r;
        float3 x = ld3(xyz_raw, fp32, row);
        rowX[r][0] = x.x; rowX[r][1] = x.y; rowX[r][2] = x.z;
        int k = k34[row];
        rowK[r] = k;
        float3 q = ld3(xyz_raw, fp32, idx3[row]);
        int ri = idx4[k];
        float3 rr = ld3(xyz_raw, fp32, ri);
        rowD[r][0] = q.x - rr.x; rowD[r][1] = q.y - rr.y; rowD[r][2] = q.z - rr.z;
        refQ[r][0] = rr.x; refQ[r][1] = rr.y; refQ[r][2] = rr.z;   // pe4 q-coords == ref
        float3 kk = ld3(xyz_raw, fp32, k);
        refK[r][0] = kk.x; refK[r][1] = kk.y; refK[r][2] = kk.z;
    }
    __syncthreads();

    // ---- build A rows = pe4[rowK[r]] via rank-6 affine (bit-identical) ----
    {
        float cc = c0[tid];
        float a0 = M1_0[tid], a1 = M1_0[256 + tid], a2 = M1_0[512 + tid];
        float b0 = M2_0[tid], b1 = M2_0[256 + tid], b2 = M2_0[512 + tid];
        for (int r = 0; r < 64; ++r) {
            float v = cc;
            v = fmaf(refQ[r][0], a0, v);
            v = fmaf(refQ[r][1], a1, v);
            v = fmaf(refQ[r][2], a2, v);
            v = fmaf(refK[r][0], b0, v);
            v = fmaf(refK[r][1], b1, v);
            v = fmaf(refK[r][2], b2, v);
            A_lds[r * 264 + tid] = f2b(v);
        }
    }
    __syncthreads();

    int wave = tid >> 6;
    int lane = tid & 63;
    int quad = lane >> 4;
    int l16 = lane & 15;
    int wc = wave * 64;

    const ushort_t* bbase[4];
#pragma unroll
    for (int nt = 0; nt < 4; ++nt)
        bbase[nt] = PT + (size_t)(wc + nt * 16 + l16) * 256 + quad * 8;

    float4v acc[4][4];
#pragma unroll
    for (int mt = 0; mt < 4; ++mt)
#pragma unroll
        for (int nt = 0; nt < 4; ++nt) acc[mt][nt] = (float4v){0.f, 0.f, 0.f, 0.f};

#pragma unroll
    for (int kt = 0; kt < 8; ++kt) {
        int c0k = kt * 32;
        short8 afr[4], bfr[4];
#pragma unroll
        for (int nt = 0; nt < 4; ++nt)
            bfr[nt] = *(const short8*)(bbase[nt] + c0k);
#pragma unroll
        for (int mt = 0; mt < 4; ++mt)
            afr[mt] = *(const short8*)&A_lds[(mt * 16 + l16) * 264 + c0k + quad * 8];
#pragma unroll
        for (int mt = 0; mt < 4; ++mt)
#pragma unroll
            for (int nt = 0; nt < 4; ++nt)
                acc[mt][nt] = __builtin_amdgcn_mfma_f32_16x16x32_bf16(
                    afr[mt], bfr[nt], acc[mt][nt], 0, 0, 0);
    }

#pragma unroll
    for (int mt = 0; mt < 4; ++mt) {
#pragma unroll
        for (int reg = 0; reg < 4; ++reg) {
            int rl = mt * 16 + quad * 4 + reg;
            float d0 = rowD[rl][0], d1 = rowD[rl][1], d2 = rowD[rl][2];
            float x0 = rowX[rl][0], x1 = rowX[rl][1], x2 = rowX[rl][2];
            int row = row0 + rl;
#pragma unroll
            for (int nt = 0; nt < 4; ++nt) {
                int col = wc + nt * 16 + l16;
                float v = acc[mt][nt][reg] + cl[col];
                v = fmaf(d0, m1l[col], v);
                v = fmaf(d1, m1l[256 + col], v);
                v = fmaf(d2, m1l[512 + col], v);
                v = fmaf(x0, m2l[col], v);
                v = fmaf(x1, m2l[256 + col], v);
                v = fmaf(x2, m2l[512 + col], v);
                size_t idx = (size_t)row * 256 + col;
                if (fp32) ((float*)outv)[o3 + idx] = v;
                else      ((bf16*)outv)[o3 + idx] = __float2bfloat16(v);
                peB_out[idx] = f2b(v);
            }
        }
    }
}

// ---------------- generic MFMA level kernel (L2/L1/L0) ----------------
__global__ __launch_bounds__(256, 2) void level_mfma(
    const void* __restrict__ xyz_raw,
    const ushort_t* __restrict__ peB_prev,
    const int* __restrict__ kmap,
    const int* __restrict__ idxQ,
    const int* __restrict__ idxR,
    const float* __restrict__ M1, const float* __restrict__ M2,
    const float* __restrict__ cvec,
    const ushort_t* __restrict__ PT,
    const int* __restrict__ flag, void* __restrict__ outv, size_t out_off,
    ushort_t* __restrict__ peB_out) {
    __shared__ float m1l[768], m2l[768], cl[256];
    __shared__ float rowD[64][3], rowX[64][3];
    __shared__ int rowK[64];
    __shared__ __align__(16) ushort_t A_lds[64 * 264];

    int tid = threadIdx.x;
    int row0 = blockIdx.x * 64;
    int fp32 = flag[0];

    for (int i = tid; i < 768; i += 256) { m1l[i] = M1[i]; m2l[i] = M2[i]; }
    cl[tid] = cvec[tid];
    if (tid < 64) {
        int r = tid, row = row0 + r;
        float3 x = ld3(xyz_raw, fp32, row);
        rowX[r][0] = x.x; rowX[r][1] = x.y; rowX[r][2] = x.z;
        int k = kmap[row];
        rowK[r] = k;
        float qx = x.x, qy = x.y, qz = x.z;
        if (idxQ) {
            float3 q = ld3(xyz_raw, fp32, idxQ[row]);
            qx = q.x; qy = q.y; qz = q.z;
        }
        int ri = idxR[k];
        float3 rr = ld3(xyz_raw, fp32, ri);
        rowD[r][0] = qx - rr.x; rowD[r][1] = qy - rr.y; rowD[r][2] = qz - rr.z;
    }
    __syncthreads();

#pragma unroll
    for (int it = 0; it < 8; ++it) {
        int lin = it * 256 + tid;
        int r = lin >> 5, ch = lin & 31;
        *(uint4*)&A_lds[r * 264 + ch * 8] =
            *(const uint4*)(peB_prev + (size_t)rowK[r] * 256 + ch * 8);
    }
    __syncthreads();

    int wave = tid >> 6;
    int lane = tid & 63;
    int quad = lane >> 4;
    int l16 = lane & 15;
    int wc = wave * 64;

    const ushort_t* bbase[4];
#pragma unroll
    for (int nt = 0; nt < 4; ++nt)
        bbase[nt] = PT + (size_t)(wc + nt * 16 + l16) * 256 + quad * 8;

    float4v acc[4][4];
#pragma unroll
    for (int mt = 0; mt < 4; ++mt)
#pragma unroll
        for (int nt = 0; nt < 4; ++nt) acc[mt][nt] = (float4v){0.f, 0.f, 0.f, 0.f};

#pragma unroll
    for (int kt = 0; kt < 8; ++kt) {
        int c0 = kt * 32;
        short8 afr[4], bfr[4];
#pragma unroll
        for (int nt = 0; nt < 4; ++nt)
            bfr[nt] = *(const short8*)(bbase[nt] + c0);
#pragma unroll
        for (int mt = 0; mt < 4; ++mt)
            afr[mt] = *(const short8*)&A_lds[(mt * 16 + l16) * 264 + c0 + quad * 8];
#pragma unroll
        for (int mt = 0; mt < 4; ++mt)
#pragma unroll
            for (int nt = 0; nt < 4; ++nt)
                acc[mt][nt] = __builtin_amdgcn_mfma_f32_16x16x32_bf16(
                    afr[mt], bfr[nt], acc[mt][nt], 0, 0, 0);
    }

#pragma unroll
    for (int mt = 0; mt < 4; ++mt) {
#pragma unroll
        for (int reg = 0; reg < 4; ++reg) {
            int rl = mt * 16 + quad * 4 + reg;
            float d0 = rowD[rl][0], d1 = rowD[rl][1], d2 = rowD[rl][2];
            float x0 = rowX[rl][0], x1 = rowX[rl][1], x2 = rowX[rl][2];
            int row = row0 + rl;
#pragma unroll
            for (int nt = 0; nt < 4; ++nt) {
                int col = wc + nt * 16 + l16;
                float v = acc[mt][nt][reg] + cl[col];
                v = fmaf(d0, m1l[col], v);
                v = fmaf(d1, m1l[256 + col], v);
                v = fmaf(d2, m1l[512 + col], v);
                v = fmaf(x0, m2l[col], v);
                v = fmaf(x1, m2l[256 + col], v);
                v = fmaf(x2, m2l[512 + col], v);
                size_t idx = (size_t)row * 256 + col;
                if (fp32) ((float*)outv)[out_off + idx] = v;
                else      ((bf16*)outv)[out_off + idx] = __float2bfloat16(v);
                if (peB_out) peB_out[idx] = f2b(v);
            }
        }
    }
}

extern "C" void kernel_launch(void* const* d_in, const int* in_sizes, int n_in,
                              void* d_out, int out_size, void* d_ws, size_t ws_size,
                              hipStream_t stream) {
    const int* idx0 = (const int*)d_in[1];
    const int* idx1 = (const int*)d_in[2];
    const int* idx2 = (const int*)d_in[3];
    const int* idx3 = (const int*)d_in[4];
    const int* idx4 = (const int*)d_in[5];

    // workspace layout (all offsets multiples of 64 floats => 16B aligned)
    float* ws = (float*)d_ws;
    int* flag = (int*)ws;            // ws[0]
    float* p = ws + 64;
    float* M1buf = p; p += 5 * 768;
    float* M2buf = p; p += 5 * 768;
    float* cbuf = p;  p += 5 * 256;
    int* k34 = (int*)p; p += 1024;
    int* k23 = (int*)p; p += 4096;
    int* k12 = (int*)p; p += 16384;
    ushort_t* pe3B = (ushort_t*)p; p += 131072;    // 1024*256 bf16
    ushort_t* pe2B = (ushort_t*)p; p += 524288;    // 4096*256 bf16
    ushort_t* pe1B = (ushort_t*)p; p += 2097152;   // 16384*256 bf16
    ushort_t* PTb = (ushort_t*)p;                  // 5 * 65536 bf16 (slots 1..4 used)

    RawArgs ra;
    ra.xyz = d_in[0];
    ra.Wall = d_in[6];
    ra.ball = d_in[7];
    for (int i = 0; i < 5; ++i) {
        ra.W[i] = d_in[8 + 2 * i];
        ra.bb[i] = d_in[9 + 2 * i];
        ra.P[i] = d_in[18 + 2 * i];
        ra.pb[i] = d_in[19 + 2 * i];
    }

    prep_nn_kernel<<<440, 512, 0, stream>>>(ra, idx1, idx2, idx3, idx4,
                                            PTb, M1buf, M2buf, cbuf,
                                            k34, k23, k12, flag);

    const size_t o4 = 0;
    const size_t o3 = (size_t)cN4 * 256;
    const size_t o2 = o3 + (size_t)cN3 * 256;
    const size_t o1 = o2 + (size_t)cN2 * 256;
    const size_t o0 = o1 + (size_t)cN1 * 256;

    level3_kernel<<<20, 256, 0, stream>>>(
        d_in[0], idx3, idx4, k34,
        M1buf, M2buf, cbuf,
        M1buf + 768, M2buf + 768, cbuf + 256,
        PTb + 1 * 65536, flag, d_out, o4, o3, pe3B);

    level_mfma<<<cN2 / 64, 256, 0, stream>>>(
        d_in[0], pe3B, k23, idx2, idx3, M1buf + 2 * 768, M2buf + 2 * 768, cbuf + 2 * 256,
        PTb + 2 * 65536, flag, d_out, o2, pe2B);
    level_mfma<<<cN1 / 64, 256, 0, stream>>>(
        d_in[0], pe2B, k12, idx1, idx2, M1buf + 3 * 768, M2buf + 3 * 768, cbuf + 3 * 256,
        PTb + 3 * 65536, flag, d_out, o1, pe1B);
    level_mfma<<<cN0 / 64, 256, 0, stream>>>(
        d_in[0], pe1B, idx0, nullptr, idx1, M1buf + 4 * 768, M2buf + 4 * 768, cbuf + 4 * 256,
        PTb + 4 * 65536, flag, d_out, o0, nullptr);
}